// Round 1
// baseline (11995.503 us; speedup 1.0000x reference)
//
#include <hip/hip_runtime.h>

// Problem constants (fixed by the reference)
#define HD   256
#define RR   3
#define N_CL 20000
#define N_DR 4000
#define F_CL 3831
#define F_DR 1024
#define NE   500000
#define NEL  200000

// ---------------------------------------------------------------------------
// Generic tiled fp32 GEMM: C[M,N] = A[M,K] @ B[K,N]
// blockIdx.z = relation r: B += r*K*N, C += r*M*N  (grid.z==1 -> no offset)
// 64x64 block tile, 256 threads, 4x4 per thread, K-step 16.
// ---------------------------------------------------------------------------
__global__ __launch_bounds__(256) void gemm64(const float* __restrict__ A,
                                              const float* __restrict__ B,
                                              float* __restrict__ C,
                                              int M, int K, int N)
{
    B += (size_t)blockIdx.z * K * N;
    C += (size_t)blockIdx.z * M * N;
    __shared__ float As[16][68];   // [k][row], padded
    __shared__ float Bs[16][64];   // [k][col]
    const int tid = threadIdx.x;
    const int tx = tid & 15, ty = tid >> 4;
    const int row0 = blockIdx.y * 64;
    const int col0 = blockIdx.x * 64;
    float acc[4][4] = {};

    for (int k0 = 0; k0 < K; k0 += 16) {
        {   // A tile: 64 rows x 16 k
            int k = tid & 15, r = tid >> 4;
            #pragma unroll
            for (int i = 0; i < 4; i++) {
                int rr = r + i * 16;
                int grow = row0 + rr, gk = k0 + k;
                As[k][rr] = (grow < M && gk < K) ? A[(size_t)grow * K + gk] : 0.f;
            }
        }
        {   // B tile: 16 k x 64 cols
            int c = tid & 63, kr = tid >> 6;
            #pragma unroll
            for (int i = 0; i < 4; i++) {
                int kk = kr + i * 4;
                int gk = k0 + kk;
                Bs[kk][c] = (gk < K) ? B[(size_t)gk * N + col0 + c] : 0.f;
            }
        }
        __syncthreads();
        #pragma unroll
        for (int kk = 0; kk < 16; kk++) {
            float4 a4 = *(const float4*)&As[kk][ty * 4];
            float4 b4 = *(const float4*)&Bs[kk][tx * 4];
            float av[4] = {a4.x, a4.y, a4.z, a4.w};
            float bv[4] = {b4.x, b4.y, b4.z, b4.w};
            #pragma unroll
            for (int i = 0; i < 4; i++)
                #pragma unroll
                for (int j = 0; j < 4; j++)
                    acc[i][j] += av[i] * bv[j];
        }
        __syncthreads();
    }
    #pragma unroll
    for (int i = 0; i < 4; i++) {
        int grow = row0 + ty * 4 + i;
        if (grow < M) {
            #pragma unroll
            for (int j = 0; j < 4; j++)
                C[(size_t)grow * N + col0 + tx * 4 + j] = acc[i][j];
        }
    }
}

// ---------------------------------------------------------------------------
// Edge aggregation: one 64-lane wave per edge; gather h[etype,src,:] (256 f32)
// and atomicAdd into sums[dst*R+etype,:]; lane 0 bumps the float count.
// ---------------------------------------------------------------------------
__global__ __launch_bounds__(256) void edge_agg(const float* __restrict__ h,  // [R,Nsrc,HD]
                                                const int* __restrict__ src,
                                                const int* __restrict__ dst,
                                                const int* __restrict__ et,
                                                int E, int Nsrc,
                                                float* __restrict__ sums,     // [Ndst*R,HD] zeroed
                                                float* __restrict__ cnt)      // [Ndst*R]    zeroed
{
    int e = blockIdx.x * 4 + (threadIdx.x >> 6);
    if (e >= E) return;
    int lane = threadIdx.x & 63;
    int s = src[e], d = dst[e], r = et[e];
    const float* hp = h + ((size_t)r * Nsrc + s) * HD;
    float* sp = sums + ((size_t)d * RR + r) * HD;
    if (lane == 0) atomicAdd(&cnt[d * RR + r], 1.0f);
    float4 v = *(const float4*)&hp[lane * 4];
    atomicAdd(&sp[lane * 4 + 0], v.x);
    atomicAdd(&sp[lane * 4 + 1], v.y);
    atomicAdd(&sp[lane * 4 + 2], v.z);
    atomicAdd(&sp[lane * 4 + 3], v.w);
}

// ---------------------------------------------------------------------------
// Finalize: z[d,:] = (opt relu)( sum_r sums[d*R+r,:]/max(cnt,1) + root[d,:] + bias )
// ---------------------------------------------------------------------------
__global__ __launch_bounds__(256) void finalize(const float* __restrict__ sums,
                                                const float* __restrict__ cnt,
                                                const float* __restrict__ rootout,
                                                const float* __restrict__ bias,
                                                float* __restrict__ z,
                                                int Ndst, int do_relu)
{
    int d = blockIdx.x;
    int hx = threadIdx.x;
    float acc = rootout[(size_t)d * HD + hx] + bias[hx];
    #pragma unroll
    for (int r = 0; r < RR; r++) {
        float c = cnt[d * RR + r];
        acc += sums[((size_t)d * RR + r) * HD + hx] * (1.0f / fmaxf(c, 1.0f));
    }
    if (do_relu) acc = fmaxf(acc, 0.f);
    z[(size_t)d * HD + hx] = acc;
}

// ---------------------------------------------------------------------------
// Decoder: per block, 16 edges. Stage z=[zcl2[row]|zdr2[col]] (16x512) in LDS,
// each thread owns one of 256 hidden cols: acc[e] = sum_k z[e][k]*w1[k][h];
// then out[e] = sum_h relu(acc+b1[h])*w2[h] + b2 via wave+LDS reduction.
// ---------------------------------------------------------------------------
__global__ __launch_bounds__(256) void decoder(const float* __restrict__ zcl,
                                               const float* __restrict__ zdr,
                                               const int* __restrict__ row,
                                               const int* __restrict__ col,
                                               const float* __restrict__ w1,  // [512,256]
                                               const float* __restrict__ b1,  // [256]
                                               const float* __restrict__ w2,  // [256]
                                               const float* __restrict__ b2,  // [1]
                                               float* __restrict__ out, int EL)
{
    __shared__ float zl[16][512];     // 32 KB
    __shared__ float part[4][16];
    const int e0 = blockIdx.x * 16;
    const int tid = threadIdx.x;

    for (int i = tid; i < 16 * 128; i += 256) {   // 128 float4 chunks per edge
        int e = i >> 7, q = i & 127;
        int ge = e0 + e;
        float4 v = make_float4(0.f, 0.f, 0.f, 0.f);
        if (ge < EL) {
            if (q < 64) v = *(const float4*)&zcl[(size_t)row[ge] * HD + q * 4];
            else        v = *(const float4*)&zdr[(size_t)col[ge] * HD + (q - 64) * 4];
        }
        *(float4*)&zl[e][q * 4] = v;
    }
    __syncthreads();

    const int h = tid;
    float acc[16] = {};
    #pragma unroll 4
    for (int k = 0; k < 512; k++) {
        float b = w1[k * HD + h];
        #pragma unroll
        for (int e = 0; e < 16; e++) acc[e] += zl[e][k] * b;
    }

    const float wh = w2[h];
    const float bb = b1[h];
    const int wave = tid >> 6, lane = tid & 63;
    #pragma unroll
    for (int e = 0; e < 16; e++) {
        float v = fmaxf(acc[e] + bb, 0.f) * wh;
        #pragma unroll
        for (int off = 32; off >= 1; off >>= 1) v += __shfl_xor(v, off, 64);
        if (lane == 0) part[wave][e] = v;
    }
    __syncthreads();
    if (tid < 16) {
        int ge = e0 + tid;
        if (ge < EL)
            out[ge] = part[0][tid] + part[1][tid] + part[2][tid] + part[3][tid] + b2[0];
    }
}

// ---------------------------------------------------------------------------
extern "C" void kernel_launch(void* const* d_in, const int* in_sizes, int n_in,
                              void* d_out, int out_size, void* d_ws, size_t ws_size,
                              hipStream_t stream)
{
    const float* x_cl   = (const float*)d_in[0];
    const float* x_dr   = (const float*)d_in[1];
    const int* src_sen  = (const int*)d_in[2];
    const int* dst_sen  = (const int*)d_in[3];
    const int* et_sen   = (const int*)d_in[4];
    const int* src_rev  = (const int*)d_in[5];
    const int* dst_rev  = (const int*)d_in[6];
    const int* et_rev   = (const int*)d_in[7];
    const int* row      = (const int*)d_in[8];
    const int* col      = (const int*)d_in[9];
    const float* W1_sen = (const float*)d_in[10];
    const float* r1_sen = (const float*)d_in[11];
    const float* b1_sen = (const float*)d_in[12];
    const float* W1_rev = (const float*)d_in[13];
    const float* r1_rev = (const float*)d_in[14];
    const float* b1_rev = (const float*)d_in[15];
    const float* W2_sen = (const float*)d_in[16];
    const float* r2_sen = (const float*)d_in[17];
    const float* b2_sen = (const float*)d_in[18];
    const float* W2_rev = (const float*)d_in[19];
    const float* r2_rev = (const float*)d_in[20];
    const float* b2_rev = (const float*)d_in[21];
    const float* lin1_w = (const float*)d_in[22];
    const float* lin1_b = (const float*)d_in[23];
    const float* lin2_w = (const float*)d_in[24];
    const float* lin2_b = (const float*)d_in[25];
    float* out = (float*)d_out;

    // ---- workspace layout (float offsets) ---- total ~221.5 MB
    float* ws = (float*)d_ws;
    float* h_sen   = ws;                         // [3,20000,256] 15,360,000
    float* h_rev   = h_sen + 15360000;           // [3, 4000,256]  3,072,000
    float* root_dr = h_rev + 3072000;            // [4000,256]     1,024,000
    float* root_cl = root_dr + 1024000;          // [20000,256]    5,120,000
    float* sums_dr = root_cl + 5120000;          // [12000,256]    3,072,000
    float* cnt_dr  = sums_dr + 3072000;          // [12000]
    float* sums_cl = cnt_dr + 12000;             // [60000,256]   15,360,000
    float* cnt_cl  = sums_cl + 15360000;         // [60000]
    float* z_dr    = cnt_cl + 60000;             // [4000,256]
    float* z_cl    = z_dr + 1024000;             // [20000,256]
    float* z_dr2   = z_cl + 5120000;             // [4000,256]
    float* z_cl2   = z_dr2 + 1024000;            // [20000,256]

    const size_t zero_bytes = (size_t)(3072000 + 12000 + 15360000 + 60000) * 4;

    dim3 blk(256);
    // ================= layer 1 =================
    hipMemsetAsync(sums_dr, 0, zero_bytes, stream);
    // h_sen[r] = x_cl @ W1_sen[r]
    gemm64<<<dim3(4, (N_CL + 63) / 64, 3), blk, 0, stream>>>(x_cl, W1_sen, h_sen, N_CL, F_CL, HD);
    // h_rev[r] = x_dr @ W1_rev[r]
    gemm64<<<dim3(4, (N_DR + 63) / 64, 3), blk, 0, stream>>>(x_dr, W1_rev, h_rev, N_DR, F_DR, HD);
    // root terms
    gemm64<<<dim3(4, (N_DR + 63) / 64, 1), blk, 0, stream>>>(x_dr, r1_sen, root_dr, N_DR, F_DR, HD);
    gemm64<<<dim3(4, (N_CL + 63) / 64, 1), blk, 0, stream>>>(x_cl, r1_rev, root_cl, N_CL, F_CL, HD);
    // aggregate
    edge_agg<<<dim3((NE + 3) / 4), blk, 0, stream>>>(h_sen, src_sen, dst_sen, et_sen, NE, N_CL, sums_dr, cnt_dr);
    edge_agg<<<dim3((NE + 3) / 4), blk, 0, stream>>>(h_rev, src_rev, dst_rev, et_rev, NE, N_DR, sums_cl, cnt_cl);
    // finalize (+relu)
    finalize<<<dim3(N_DR), blk, 0, stream>>>(sums_dr, cnt_dr, root_dr, b1_sen, z_dr, N_DR, 1);
    finalize<<<dim3(N_CL), blk, 0, stream>>>(sums_cl, cnt_cl, root_cl, b1_rev, z_cl, N_CL, 1);

    // ================= layer 2 (reuse buffers) =================
    hipMemsetAsync(sums_dr, 0, zero_bytes, stream);
    gemm64<<<dim3(4, (N_CL + 63) / 64, 3), blk, 0, stream>>>(z_cl, W2_sen, h_sen, N_CL, HD, HD);
    gemm64<<<dim3(4, (N_DR + 63) / 64, 3), blk, 0, stream>>>(z_dr, W2_rev, h_rev, N_DR, HD, HD);
    gemm64<<<dim3(4, (N_DR + 63) / 64, 1), blk, 0, stream>>>(z_dr, r2_sen, root_dr, N_DR, HD, HD);
    gemm64<<<dim3(4, (N_CL + 63) / 64, 1), blk, 0, stream>>>(z_cl, r2_rev, root_cl, N_CL, HD, HD);
    edge_agg<<<dim3((NE + 3) / 4), blk, 0, stream>>>(h_sen, src_sen, dst_sen, et_sen, NE, N_CL, sums_dr, cnt_dr);
    edge_agg<<<dim3((NE + 3) / 4), blk, 0, stream>>>(h_rev, src_rev, dst_rev, et_rev, NE, N_DR, sums_cl, cnt_cl);
    finalize<<<dim3(N_DR), blk, 0, stream>>>(sums_dr, cnt_dr, root_dr, b2_sen, z_dr2, N_DR, 0);
    finalize<<<dim3(N_CL), blk, 0, stream>>>(sums_cl, cnt_cl, root_cl, b2_rev, z_cl2, N_CL, 0);

    // ================= decoder =================
    decoder<<<dim3((NEL + 15) / 16), blk, 0, stream>>>(z_cl2, z_dr2, row, col,
                                                       lin1_w, lin1_b, lin2_w, lin2_b,
                                                       out, NEL);
}

// Round 3
// 5256.199 us; speedup vs baseline: 2.2822x; 2.2822x over previous
//
#include <hip/hip_runtime.h>

// Problem constants (fixed by the reference)
#define HD   256
#define RR   3
#define N_CL 20000
#define N_DR 4000
#define F_CL 3831
#define F_DR 1024
#define NE   500000
#define NEL  200000

// ---------------------------------------------------------------------------
// Generic tiled fp32 GEMM: C[M,N] = A[M,K] @ B[K,N]
// blockIdx.z = relation r: B += r*K*N, C += r*M*N  (grid.z==1 -> no offset)
// 64x64 block tile, 256 threads, 4x4 per thread, K-step 16.
// ---------------------------------------------------------------------------
__global__ __launch_bounds__(256) void gemm64(const float* __restrict__ A,
                                              const float* __restrict__ B,
                                              float* __restrict__ C,
                                              int M, int K, int N)
{
    B += (size_t)blockIdx.z * K * N;
    C += (size_t)blockIdx.z * M * N;
    __shared__ float As[16][68];   // [k][row], padded
    __shared__ float Bs[16][64];   // [k][col]
    const int tid = threadIdx.x;
    const int tx = tid & 15, ty = tid >> 4;
    const int row0 = blockIdx.y * 64;
    const int col0 = blockIdx.x * 64;
    float acc[4][4] = {};

    for (int k0 = 0; k0 < K; k0 += 16) {
        {   // A tile: 64 rows x 16 k
            int k = tid & 15, r = tid >> 4;
            #pragma unroll
            for (int i = 0; i < 4; i++) {
                int rr = r + i * 16;
                int grow = row0 + rr, gk = k0 + k;
                As[k][rr] = (grow < M && gk < K) ? A[(size_t)grow * K + gk] : 0.f;
            }
        }
        {   // B tile: 16 k x 64 cols
            int c = tid & 63, kr = tid >> 6;
            #pragma unroll
            for (int i = 0; i < 4; i++) {
                int kk = kr + i * 4;
                int gk = k0 + kk;
                Bs[kk][c] = (gk < K) ? B[(size_t)gk * N + col0 + c] : 0.f;
            }
        }
        __syncthreads();
        #pragma unroll
        for (int kk = 0; kk < 16; kk++) {
            float4 a4 = *(const float4*)&As[kk][ty * 4];
            float4 b4 = *(const float4*)&Bs[kk][tx * 4];
            float av[4] = {a4.x, a4.y, a4.z, a4.w};
            float bv[4] = {b4.x, b4.y, b4.z, b4.w};
            #pragma unroll
            for (int i = 0; i < 4; i++)
                #pragma unroll
                for (int j = 0; j < 4; j++)
                    acc[i][j] += av[i] * bv[j];
        }
        __syncthreads();
    }
    #pragma unroll
    for (int i = 0; i < 4; i++) {
        int grow = row0 + ty * 4 + i;
        if (grow < M) {
            #pragma unroll
            for (int j = 0; j < 4; j++)
                C[(size_t)grow * N + col0 + tx * 4 + j] = acc[i][j];
        }
    }
}

// ---------------------------------------------------------------------------
// CSR build: histogram -> exclusive scan -> scatter src into segment order.
// Segment key = dst*RR + etype. Built once per launch, reused by both layers.
// ---------------------------------------------------------------------------
__global__ __launch_bounds__(256) void count_seg(const int* __restrict__ dst,
                                                 const int* __restrict__ et,
                                                 int E, int* __restrict__ cnt)
{
    int e = blockIdx.x * 256 + threadIdx.x;
    if (e < E) atomicAdd(&cnt[dst[e] * RR + et[e]], 1);
}

// single-workgroup exclusive scan (n up to ~60000, 1024 threads)
__global__ __launch_bounds__(1024) void exscan(const int* __restrict__ cnt,
                                               int* __restrict__ base, int n)
{
    __shared__ int wsum[16];
    __shared__ int carry_s;
    const int tid = threadIdx.x;
    const int lane = tid & 63, wv = tid >> 6;
    if (tid == 0) carry_s = 0;
    __syncthreads();
    for (int i0 = 0; i0 < n; i0 += 1024) {
        int i = i0 + tid;
        int v = (i < n) ? cnt[i] : 0;
        int s = v;                                  // inclusive wave scan
        #pragma unroll
        for (int off = 1; off < 64; off <<= 1) {
            int t = __shfl_up(s, off, 64);
            if (lane >= off) s += t;
        }
        if (lane == 63) wsum[wv] = s;
        __syncthreads();
        if (wv == 0 && lane < 16) {                 // scan the 16 wave sums
            int t = wsum[lane];
            #pragma unroll
            for (int off = 1; off < 16; off <<= 1) {
                int u = __shfl_up(t, off, 16);
                if ((lane & 15) >= off) t += u;
            }
            wsum[lane] = t;                         // inclusive
        }
        __syncthreads();
        int waveoff = (wv == 0) ? 0 : wsum[wv - 1];
        int carry = carry_s;
        if (i < n) base[i] = carry + waveoff + s - v;   // exclusive
        __syncthreads();
        if (tid == 1023) carry_s = carry + wsum[15];
        __syncthreads();
    }
}

__global__ __launch_bounds__(256) void scatter_seg(const int* __restrict__ src,
                                                   const int* __restrict__ dst,
                                                   const int* __restrict__ et,
                                                   int E,
                                                   const int* __restrict__ base,
                                                   int* __restrict__ fill,
                                                   int* __restrict__ ssrc)
{
    int e = blockIdx.x * 256 + threadIdx.x;
    if (e < E) {
        int seg = dst[e] * RR + et[e];
        int p = base[seg] + atomicAdd(&fill[seg], 1);
        ssrc[p] = src[e];
    }
}

// ---------------------------------------------------------------------------
// Fused aggregate + finalize: one block (256 thr) per dst node. For r=0..2,
// loop the segment's sorted src list, coalesced-read h rows, accumulate in
// registers; z = sum_r acc_r/max(cnt,1) + root + bias (+relu). No atomics.
// ---------------------------------------------------------------------------
__global__ __launch_bounds__(256) void agg_fin(const float* __restrict__ h,   // [R,Nsrc,HD]
                                               const int* __restrict__ base,
                                               const int* __restrict__ cnt,
                                               const int* __restrict__ ssrc,
                                               const float* __restrict__ rootout,
                                               const float* __restrict__ bias,
                                               float* __restrict__ z,
                                               int Ndst, int Nsrc, int do_relu)
{
    const int d = blockIdx.x;
    const int hx = threadIdx.x;
    float acc = rootout[(size_t)d * HD + hx] + bias[hx];
    #pragma unroll
    for (int r = 0; r < RR; r++) {
        const int seg = d * RR + r;
        const int b0 = base[seg], c = cnt[seg];
        const float* hr = h + (size_t)r * Nsrc * HD + hx;
        float sA = 0.f, sB = 0.f;
        int i = 0;
        for (; i + 1 < c; i += 2) {
            int s0 = ssrc[b0 + i], s1 = ssrc[b0 + i + 1];
            sA += hr[(size_t)s0 * HD];
            sB += hr[(size_t)s1 * HD];
        }
        if (i < c) sA += hr[(size_t)ssrc[b0 + i] * HD];
        acc += (sA + sB) * (1.0f / fmaxf((float)c, 1.0f));
    }
    if (do_relu) acc = fmaxf(acc, 0.f);
    z[(size_t)d * HD + hx] = acc;
}

// ---------------------------------------------------------------------------
// Decoder: per block, 16 edges. Stage z=[zcl2[row]|zdr2[col]] (16x512) in LDS,
// each thread owns one of 256 hidden cols; wave+LDS reduce to the scalar out.
// ---------------------------------------------------------------------------
__global__ __launch_bounds__(256) void decoder(const float* __restrict__ zcl,
                                               const float* __restrict__ zdr,
                                               const int* __restrict__ row,
                                               const int* __restrict__ col,
                                               const float* __restrict__ w1,  // [512,256]
                                               const float* __restrict__ b1,  // [256]
                                               const float* __restrict__ w2,  // [256]
                                               const float* __restrict__ b2,  // [1]
                                               float* __restrict__ out, int EL)
{
    __shared__ float zl[16][512];     // 32 KB
    __shared__ float part[4][16];
    const int e0 = blockIdx.x * 16;
    const int tid = threadIdx.x;

    for (int i = tid; i < 16 * 128; i += 256) {   // 128 float4 chunks per edge
        int e = i >> 7, q = i & 127;
        int ge = e0 + e;
        float4 v = make_float4(0.f, 0.f, 0.f, 0.f);
        if (ge < EL) {
            if (q < 64) v = *(const float4*)&zcl[(size_t)row[ge] * HD + q * 4];
            else        v = *(const float4*)&zdr[(size_t)col[ge] * HD + (q - 64) * 4];
        }
        *(float4*)&zl[e][q * 4] = v;
    }
    __syncthreads();

    const int h = tid;
    float acc[16] = {};
    #pragma unroll 4
    for (int k = 0; k < 512; k++) {
        float b = w1[k * HD + h];
        #pragma unroll
        for (int e = 0; e < 16; e++) acc[e] += zl[e][k] * b;
    }

    const float wh = w2[h];
    const float bb = b1[h];
    const int wave = tid >> 6, lane = tid & 63;
    #pragma unroll
    for (int e = 0; e < 16; e++) {
        float v = fmaxf(acc[e] + bb, 0.f) * wh;
        #pragma unroll
        for (int off = 32; off >= 1; off >>= 1) v += __shfl_xor(v, off, 64);
        if (lane == 0) part[wave][e] = v;
    }
    __syncthreads();
    if (tid < 16) {
        int ge = e0 + tid;
        if (ge < EL)
            out[ge] = part[0][tid] + part[1][tid] + part[2][tid] + part[3][tid] + b2[0];
    }
}

// ---------------------------------------------------------------------------
extern "C" void kernel_launch(void* const* d_in, const int* in_sizes, int n_in,
                              void* d_out, int out_size, void* d_ws, size_t ws_size,
                              hipStream_t stream)
{
    const float* x_cl   = (const float*)d_in[0];
    const float* x_dr   = (const float*)d_in[1];
    const int* src_sen  = (const int*)d_in[2];
    const int* dst_sen  = (const int*)d_in[3];
    const int* et_sen   = (const int*)d_in[4];
    const int* src_rev  = (const int*)d_in[5];
    const int* dst_rev  = (const int*)d_in[6];
    const int* et_rev   = (const int*)d_in[7];
    const int* row      = (const int*)d_in[8];
    const int* col      = (const int*)d_in[9];
    const float* W1_sen = (const float*)d_in[10];
    const float* r1_sen = (const float*)d_in[11];
    const float* b1_sen = (const float*)d_in[12];
    const float* W1_rev = (const float*)d_in[13];
    const float* r1_rev = (const float*)d_in[14];
    const float* b1_rev = (const float*)d_in[15];
    const float* W2_sen = (const float*)d_in[16];
    const float* r2_sen = (const float*)d_in[17];
    const float* b2_sen = (const float*)d_in[18];
    const float* W2_rev = (const float*)d_in[19];
    const float* r2_rev = (const float*)d_in[20];
    const float* b2_rev = (const float*)d_in[21];
    const float* lin1_w = (const float*)d_in[22];
    const float* lin1_b = (const float*)d_in[23];
    const float* lin2_w = (const float*)d_in[24];
    const float* lin2_b = (const float*)d_in[25];
    float* out = (float*)d_out;

    // ---- workspace layout ----
    float* ws = (float*)d_ws;
    float* h_sen   = ws;                         // [3,20000,256] 15,360,000
    float* h_rev   = h_sen + 15360000;           // [3, 4000,256]  3,072,000
    float* root_dr = h_rev + 3072000;            // [4000,256]     1,024,000
    float* root_cl = root_dr + 1024000;          // [20000,256]    5,120,000
    float* z_dr    = root_cl + 5120000;          // [4000,256]
    float* z_cl    = z_dr + 1024000;             // [20000,256]
    float* z_dr2   = z_cl + 5120000;             // [4000,256]
    float* z_cl2   = z_dr2 + 1024000;            // [20000,256]
    int* ip        = (int*)(z_cl2 + 5120000);
    // zeroed region (contiguous): cnt_sen, fill_sen, cnt_rev, fill_rev
    int* cnt_sen   = ip;                         // [12000]
    int* fill_sen  = cnt_sen + 12000;            // [12000]
    int* cnt_rev   = fill_sen + 12000;           // [60000]
    int* fill_rev  = cnt_rev + 60000;            // [60000]
    int* base_sen  = fill_rev + 60000;           // [12000]
    int* base_rev  = base_sen + 12000;           // [60000]
    int* ssrc_sen  = base_rev + 60000;           // [500000]
    int* ssrc_rev  = ssrc_sen + 500000;          // [500000]

    dim3 blk(256);
    const int NSEG_SEN = N_DR * RR;   // 12000
    const int NSEG_REV = N_CL * RR;   // 60000

    // ================= CSR build (once, reused by both layers) =============
    hipMemsetAsync(cnt_sen, 0, (size_t)(12000 + 12000 + 60000 + 60000) * 4, stream);
    count_seg<<<dim3((NE + 255) / 256), blk, 0, stream>>>(dst_sen, et_sen, NE, cnt_sen);
    count_seg<<<dim3((NE + 255) / 256), blk, 0, stream>>>(dst_rev, et_rev, NE, cnt_rev);
    exscan<<<dim3(1), dim3(1024), 0, stream>>>(cnt_sen, base_sen, NSEG_SEN);
    exscan<<<dim3(1), dim3(1024), 0, stream>>>(cnt_rev, base_rev, NSEG_REV);
    scatter_seg<<<dim3((NE + 255) / 256), blk, 0, stream>>>(src_sen, dst_sen, et_sen, NE,
                                                            base_sen, fill_sen, ssrc_sen);
    scatter_seg<<<dim3((NE + 255) / 256), blk, 0, stream>>>(src_rev, dst_rev, et_rev, NE,
                                                            base_rev, fill_rev, ssrc_rev);

    // ================= layer 1 =================
    gemm64<<<dim3(4, (N_CL + 63) / 64, 3), blk, 0, stream>>>(x_cl, W1_sen, h_sen, N_CL, F_CL, HD);
    gemm64<<<dim3(4, (N_DR + 63) / 64, 3), blk, 0, stream>>>(x_dr, W1_rev, h_rev, N_DR, F_DR, HD);
    gemm64<<<dim3(4, (N_DR + 63) / 64, 1), blk, 0, stream>>>(x_dr, r1_sen, root_dr, N_DR, F_DR, HD);
    gemm64<<<dim3(4, (N_CL + 63) / 64, 1), blk, 0, stream>>>(x_cl, r1_rev, root_cl, N_CL, F_CL, HD);
    agg_fin<<<dim3(N_DR), blk, 0, stream>>>(h_sen, base_sen, cnt_sen, ssrc_sen,
                                            root_dr, b1_sen, z_dr, N_DR, N_CL, 1);
    agg_fin<<<dim3(N_CL), blk, 0, stream>>>(h_rev, base_rev, cnt_rev, ssrc_rev,
                                            root_cl, b1_rev, z_cl, N_CL, N_DR, 1);

    // ================= layer 2 (reuse h/root buffers) =================
    gemm64<<<dim3(4, (N_CL + 63) / 64, 3), blk, 0, stream>>>(z_cl, W2_sen, h_sen, N_CL, HD, HD);
    gemm64<<<dim3(4, (N_DR + 63) / 64, 3), blk, 0, stream>>>(z_dr, W2_rev, h_rev, N_DR, HD, HD);
    gemm64<<<dim3(4, (N_DR + 63) / 64, 1), blk, 0, stream>>>(z_dr, r2_sen, root_dr, N_DR, HD, HD);
    gemm64<<<dim3(4, (N_CL + 63) / 64, 1), blk, 0, stream>>>(z_cl, r2_rev, root_cl, N_CL, HD, HD);
    agg_fin<<<dim3(N_DR), blk, 0, stream>>>(h_sen, base_sen, cnt_sen, ssrc_sen,
                                            root_dr, b2_sen, z_dr2, N_DR, N_CL, 0);
    agg_fin<<<dim3(N_CL), blk, 0, stream>>>(h_rev, base_rev, cnt_rev, ssrc_rev,
                                            root_cl, b2_rev, z_cl2, N_CL, N_DR, 0);

    // ================= decoder =================
    decoder<<<dim3((NEL + 15) / 16), blk, 0, stream>>>(z_cl2, z_dr2, row, col,
                                                       lin1_w, lin1_b, lin2_w, lin2_b,
                                                       out, NEL);
}

// Round 4
// 1742.199 us; speedup vs baseline: 6.8853x; 3.0170x over previous
//
#include <hip/hip_runtime.h>

// Problem constants (fixed by the reference)
#define HD   256
#define RR   3
#define N_CL 20000
#define N_DR 4000
#define F_CL 3831
#define F_DR 1024
#define NE   500000
#define NEL  200000

typedef short bf8 __attribute__((ext_vector_type(8)));   // 8 bf16 (4 VGPRs)
typedef float f4  __attribute__((ext_vector_type(4)));   // MFMA acc

#define AS1(p) ((const __attribute__((address_space(1))) void*)(p))
#define AS3(p) ((__attribute__((address_space(3))) void*)(p))

__device__ __forceinline__ unsigned short f2bf(float f) {
    union { float f; unsigned u; } v; v.f = f;
    return (unsigned short)((v.u + 0x7fffu + ((v.u >> 16) & 1u)) >> 16);
}

// ---------------------------------------------------------------------------
// cast fp32 [M][K] -> bf16 [Mp][Kp], zero pad (rows >= M and cols >= K)
// ---------------------------------------------------------------------------
__global__ __launch_bounds__(256) void cast_pad(const float* __restrict__ in,
                                                unsigned short* __restrict__ out,
                                                int M, int K, int Kp, long total8)
{
    long idx = (long)blockIdx.x * 256 + threadIdx.x;   // one 8-elem chunk
    if (idx >= total8) return;
    int kp8 = Kp >> 3;
    int r  = (int)(idx / kp8);
    int c8 = (int)(idx % kp8) * 8;
    bf8 o;
    #pragma unroll
    for (int j = 0; j < 8; j++) {
        int c = c8 + j;
        float x = (r < M && c < K) ? in[(size_t)r * K + c] : 0.f;
        o[j] = (short)f2bf(x);
    }
    *(bf8*)&out[(size_t)idx * 8] = o;
}

// ---------------------------------------------------------------------------
// transpose-cast: in [rels][K][N] fp32 -> out [rels][N][Kp] bf16, zero K-pad
// grid: (Kp/32, N/32, rels), 256 threads
// ---------------------------------------------------------------------------
__global__ __launch_bounds__(256) void cast_t(const float* __restrict__ in,
                                              unsigned short* __restrict__ out,
                                              int K, int N, int Kp)
{
    in  += (size_t)blockIdx.z * K * N;
    out += (size_t)blockIdx.z * N * Kp;
    __shared__ float t[32][33];
    int k0 = blockIdx.x * 32, n0 = blockIdx.y * 32;
    int tx = threadIdx.x & 31, ty = threadIdx.x >> 5;   // ty 0..7
    #pragma unroll
    for (int i = 0; i < 4; i++) {
        int k = k0 + ty + i * 8;
        t[ty + i * 8][tx] = (k < K) ? in[(size_t)k * N + n0 + tx] : 0.f;
    }
    __syncthreads();
    #pragma unroll
    for (int i = 0; i < 4; i++) {
        int n = ty + i * 8;
        out[(size_t)(n0 + n) * Kp + k0 + tx] = f2bf(t[tx][n]);
    }
}

// ---------------------------------------------------------------------------
// bf16 MFMA GEMM: C[z][M][N]f32 = A[Mp][Kp]bf16 @ Bt[z][N][Kp]bf16^T
// 128x128 tile, BK=32, 4 waves (2x2), 4x4 fragments of 16x16x32 each.
// LDS layout [k8block][row][8] -> fragment ds_read_b128 at 16B lane stride
// (2-way bank alias = free). Staged via global_load_lds width 16.
// ---------------------------------------------------------------------------
__global__ __launch_bounds__(256) void mgemm(const unsigned short* __restrict__ A,
                                             const unsigned short* __restrict__ Bt,
                                             float* __restrict__ C,
                                             int M, int Kp, int N)
{
    Bt += (size_t)blockIdx.z * N * Kp;
    C  += (size_t)blockIdx.z * M * N;
    __shared__ unsigned short As[4 * 128 * 8];   // 8 KB
    __shared__ unsigned short Bs[4 * 128 * 8];   // 8 KB
    const int tid = threadIdx.x;
    const int lane = tid & 63, w = tid >> 6;
    const int lo = lane & 15, hi = lane >> 4;
    const int wr = w >> 1, wc = w & 1;
    const int row0 = blockIdx.y * 128, col0 = blockIdx.x * 128;

    const int c1 = tid, c2 = tid + 256;          // chunk ids (0..511)
    const unsigned short* ga0 = A  + (size_t)(row0 + (c1 & 127)) * Kp + (c1 >> 7) * 8;
    const unsigned short* ga1 = A  + (size_t)(row0 + (c2 & 127)) * Kp + (c2 >> 7) * 8;
    const unsigned short* gb0 = Bt + (size_t)(col0 + (c1 & 127)) * Kp + (c1 >> 7) * 8;
    const unsigned short* gb1 = Bt + (size_t)(col0 + (c2 & 127)) * Kp + (c2 >> 7) * 8;

    f4 acc[4][4] = {};

    for (int k0 = 0; k0 < Kp; k0 += 32) {
        __builtin_amdgcn_global_load_lds(AS1(ga0 + k0), AS3(&As[c1 * 8]), 16, 0, 0);
        __builtin_amdgcn_global_load_lds(AS1(ga1 + k0), AS3(&As[c2 * 8]), 16, 0, 0);
        __builtin_amdgcn_global_load_lds(AS1(gb0 + k0), AS3(&Bs[c1 * 8]), 16, 0, 0);
        __builtin_amdgcn_global_load_lds(AS1(gb1 + k0), AS3(&Bs[c2 * 8]), 16, 0, 0);
        __syncthreads();

        bf8 af[4], bb[4];
        #pragma unroll
        for (int m = 0; m < 4; m++)
            af[m] = *(const bf8*)&As[(hi * 128 + wr * 64 + m * 16 + lo) * 8];
        #pragma unroll
        for (int n = 0; n < 4; n++)
            bb[n] = *(const bf8*)&Bs[(hi * 128 + wc * 64 + n * 16 + lo) * 8];
        #pragma unroll
        for (int m = 0; m < 4; m++)
            #pragma unroll
            for (int n = 0; n < 4; n++)
                acc[m][n] = __builtin_amdgcn_mfma_f32_16x16x32_bf16(af[m], bb[n], acc[m][n], 0, 0, 0);
        __syncthreads();
    }

    #pragma unroll
    for (int m = 0; m < 4; m++) {
        #pragma unroll
        for (int j = 0; j < 4; j++) {
            int row = row0 + wr * 64 + m * 16 + hi * 4 + j;
            if (row < M) {
                #pragma unroll
                for (int n = 0; n < 4; n++)
                    C[(size_t)row * N + col0 + wc * 64 + n * 16 + lo] = acc[m][n][j];
            }
        }
    }
}

// ---------------------------------------------------------------------------
// CSR build: histogram -> exclusive scan -> scatter src into segment order.
// ---------------------------------------------------------------------------
__global__ __launch_bounds__(256) void count_seg(const int* __restrict__ dst,
                                                 const int* __restrict__ et,
                                                 int E, int* __restrict__ cnt)
{
    int e = blockIdx.x * 256 + threadIdx.x;
    if (e < E) atomicAdd(&cnt[dst[e] * RR + et[e]], 1);
}

__global__ __launch_bounds__(1024) void exscan(const int* __restrict__ cnt,
                                               int* __restrict__ base, int n)
{
    __shared__ int wsum[16];
    __shared__ int carry_s;
    const int tid = threadIdx.x;
    const int lane = tid & 63, wv = tid >> 6;
    if (tid == 0) carry_s = 0;
    __syncthreads();
    for (int i0 = 0; i0 < n; i0 += 1024) {
        int i = i0 + tid;
        int v = (i < n) ? cnt[i] : 0;
        int s = v;
        #pragma unroll
        for (int off = 1; off < 64; off <<= 1) {
            int t = __shfl_up(s, off, 64);
            if (lane >= off) s += t;
        }
        if (lane == 63) wsum[wv] = s;
        __syncthreads();
        if (wv == 0 && lane < 16) {
            int t = wsum[lane];
            #pragma unroll
            for (int off = 1; off < 16; off <<= 1) {
                int u = __shfl_up(t, off, 16);
                if ((lane & 15) >= off) t += u;
            }
            wsum[lane] = t;
        }
        __syncthreads();
        int waveoff = (wv == 0) ? 0 : wsum[wv - 1];
        int carry = carry_s;
        if (i < n) base[i] = carry + waveoff + s - v;
        __syncthreads();
        if (tid == 1023) carry_s = carry + wsum[15];
        __syncthreads();
    }
}

__global__ __launch_bounds__(256) void scatter_seg(const int* __restrict__ src,
                                                   const int* __restrict__ dst,
                                                   const int* __restrict__ et,
                                                   int E,
                                                   const int* __restrict__ base,
                                                   int* __restrict__ fill,
                                                   int* __restrict__ ssrc)
{
    int e = blockIdx.x * 256 + threadIdx.x;
    if (e < E) {
        int seg = dst[e] * RR + et[e];
        int p = base[seg] + atomicAdd(&fill[seg], 1);
        ssrc[p] = src[e];
    }
}

// ---------------------------------------------------------------------------
// Fused aggregate + finalize, writing bf16 directly (feeds next GEMM/decoder).
// One block per dst node; no atomics.
// ---------------------------------------------------------------------------
template<int DO_RELU>
__global__ __launch_bounds__(256) void agg_fin(const float* __restrict__ h,   // [R,Nsrc,HD]
                                               const int* __restrict__ base,
                                               const int* __restrict__ cnt,
                                               const int* __restrict__ ssrc,
                                               const float* __restrict__ rootout,
                                               const float* __restrict__ bias,
                                               unsigned short* __restrict__ zb, // [>=Ndst][HD] bf16
                                               int Nsrc)
{
    const int d = blockIdx.x;
    const int hx = threadIdx.x;
    float acc = rootout[(size_t)d * HD + hx] + bias[hx];
    #pragma unroll
    for (int r = 0; r < RR; r++) {
        const int seg = d * RR + r;
        const int b0 = base[seg], c = cnt[seg];
        const float* hr = h + (size_t)r * Nsrc * HD + hx;
        float sA = 0.f, sB = 0.f;
        int i = 0;
        for (; i + 1 < c; i += 2) {
            int s0 = ssrc[b0 + i], s1 = ssrc[b0 + i + 1];
            sA += hr[(size_t)s0 * HD];
            sB += hr[(size_t)s1 * HD];
        }
        if (i < c) sA += hr[(size_t)ssrc[b0 + i] * HD];
        acc += (sA + sB) * (1.0f / fmaxf((float)c, 1.0f));
    }
    if (DO_RELU) acc = fmaxf(acc, 0.f);
    zb[(size_t)d * HD + hx] = f2bf(acc);
}

// ---------------------------------------------------------------------------
// Decoder as gathered-A MFMA GEMM. Per block: 64 edges x 256 hidden, K=512
// (first 256 from Zcl[row[e]], last 256 from Zdr[col[e]], both bf16).
// 4 waves split the 256 cols; each computes rows 0..63 x 64 cols (4x4 frags).
// Epilogue: relu(acc+b1)*w2, reduce over cols (xor-shfl within 16-group,
// then LDS across waves), +b2 -> out[e].
// ---------------------------------------------------------------------------
__global__ __launch_bounds__(256) void decoder_m(const unsigned short* __restrict__ Zcl, // [N_CL][256]
                                                 const unsigned short* __restrict__ Zdr, // [N_DR][256]
                                                 const int* __restrict__ row,
                                                 const int* __restrict__ col,
                                                 const unsigned short* __restrict__ W1t, // [256][512]
                                                 const float* __restrict__ b1,
                                                 const float* __restrict__ w2,
                                                 const float* __restrict__ b2,
                                                 float* __restrict__ out)
{
    __shared__ unsigned short As[4 * 64 * 8];     // 4 KB  [k8][edge][8]
    __shared__ unsigned short Bs[4 * 256 * 8];    // 16 KB [k8][colrow][8]
    __shared__ float dec[64][4];
    const int tid = threadIdx.x;
    const int lane = tid & 63, w = tid >> 6;
    const int lo = lane & 15, hi = lane >> 4;
    const int e0 = blockIdx.x * 64;

    // A staging: wave w stages k8-block b=w, edge rows r=lane (per-lane gather)
    const int eA = e0 + lane;
    const int ri = (eA < NEL) ? row[eA] : 0;
    const int ci = (eA < NEL) ? col[eA] : 0;
    const unsigned short* zclp = Zcl + (size_t)ri * HD;
    const unsigned short* zdrp = Zdr + (size_t)ci * HD;

    float b1v[4], w2v[4];
    #pragma unroll
    for (int n = 0; n < 4; n++) {
        int c = w * 64 + n * 16 + lo;
        b1v[n] = b1[c];
        w2v[n] = w2[c];
    }

    f4 acc[4][4] = {};

    for (int k0 = 0; k0 < 512; k0 += 32) {
        {   // A: 256 chunks total, 1 per thread; k = k0 + w*8 (wave-uniform)
            int k = k0 + w * 8;
            const unsigned short* ga = (k < 256) ? (zclp + k) : (zdrp + (k - 256));
            __builtin_amdgcn_global_load_lds(AS1(ga), AS3(&As[(w * 64 + lane) * 8]), 16, 0, 0);
        }
        #pragma unroll
        for (int i = 0; i < 4; i++) {   // B: 1024 chunks, 4 per thread
            const unsigned short* gb = W1t + (size_t)tid * 512 + k0 + i * 8;
            __builtin_amdgcn_global_load_lds(AS1(gb), AS3(&Bs[(i * 256 + tid) * 8]), 16, 0, 0);
        }
        __syncthreads();

        bf8 af[4], bb[4];
        #pragma unroll
        for (int m = 0; m < 4; m++)
            af[m] = *(const bf8*)&As[(hi * 64 + m * 16 + lo) * 8];
        #pragma unroll
        for (int n = 0; n < 4; n++)
            bb[n] = *(const bf8*)&Bs[(hi * 256 + w * 64 + n * 16 + lo) * 8];
        #pragma unroll
        for (int m = 0; m < 4; m++)
            #pragma unroll
            for (int n = 0; n < 4; n++)
                acc[m][n] = __builtin_amdgcn_mfma_f32_16x16x32_bf16(af[m], bb[n], acc[m][n], 0, 0, 0);
        __syncthreads();
    }

    // epilogue: out[e] = sum_c relu(acc[e][c] + b1[c]) * w2[c] + b2
    #pragma unroll
    for (int m = 0; m < 4; m++) {
        float s[4];
        #pragma unroll
        for (int j = 0; j < 4; j++) {
            float v = 0.f;
            #pragma unroll
            for (int n = 0; n < 4; n++)
                v += fmaxf(acc[m][n][j] + b1v[n], 0.f) * w2v[n];
            #pragma unroll
            for (int off = 1; off < 16; off <<= 1) v += __shfl_xor(v, off, 64);
            s[j] = v;
        }
        if (lo == 0) {
            #pragma unroll
            for (int j = 0; j < 4; j++)
                dec[m * 16 + hi * 4 + j][w] = s[j];
        }
    }
    __syncthreads();
    if (tid < 64) {
        int ge = e0 + tid;
        if (ge < NEL)
            out[ge] = dec[tid][0] + dec[tid][1] + dec[tid][2] + dec[tid][3] + b2[0];
    }
}

// ---------------------------------------------------------------------------
extern "C" void kernel_launch(void* const* d_in, const int* in_sizes, int n_in,
                              void* d_out, int out_size, void* d_ws, size_t ws_size,
                              hipStream_t stream)
{
    const float* x_cl   = (const float*)d_in[0];
    const float* x_dr   = (const float*)d_in[1];
    const int* src_sen  = (const int*)d_in[2];
    const int* dst_sen  = (const int*)d_in[3];
    const int* et_sen   = (const int*)d_in[4];
    const int* src_rev  = (const int*)d_in[5];
    const int* dst_rev  = (const int*)d_in[6];
    const int* et_rev   = (const int*)d_in[7];
    const int* row      = (const int*)d_in[8];
    const int* col      = (const int*)d_in[9];
    const float* W1_sen = (const float*)d_in[10];
    const float* r1_sen = (const float*)d_in[11];
    const float* b1_sen = (const float*)d_in[12];
    const float* W1_rev = (const float*)d_in[13];
    const float* r1_rev = (const float*)d_in[14];
    const float* b1_rev = (const float*)d_in[15];
    const float* W2_sen = (const float*)d_in[16];
    const float* r2_sen = (const float*)d_in[17];
    const float* b2_sen = (const float*)d_in[18];
    const float* W2_rev = (const float*)d_in[19];
    const float* r2_rev = (const float*)d_in[20];
    const float* b2_rev = (const float*)d_in[21];
    const float* lin1_w = (const float*)d_in[22];
    const float* lin1_b = (const float*)d_in[23];
    const float* lin2_w = (const float*)d_in[24];
    const float* lin2_b = (const float*)d_in[25];
    float* out = (float*)d_out;

    // padded dims
    const int KP_CL = 3840;   // F_CL=3831 -> pad 3840 (mult 32)
    const int MP_CL = 20096;  // 157*128
    const int MP_DR = 4096;   // 32*128

    // ---- workspace layout ----
    float* ws = (float*)d_ws;
    float* h_sen   = ws;                          // [3][20000][256]
    float* h_rev   = h_sen + 15360000;            // [3][4000][256]
    float* root_dr = h_rev + 3072000;             // [4000][256]
    float* root_cl = root_dr + 1024000;           // [20000][256]
    unsigned short* us = (unsigned short*)(root_cl + 5120000);
    unsigned short* Axcl   = us;                  // [20096][3840]
    unsigned short* Axdr   = Axcl + (size_t)MP_CL * KP_CL;   // [4096][1024]
    unsigned short* Azcl   = Axdr + (size_t)MP_DR * F_DR;    // [20096][256]
    unsigned short* Azdr   = Azcl + (size_t)MP_CL * HD;      // [4096][256]
    unsigned short* Bzcl2  = Azdr + (size_t)MP_DR * HD;      // [20000][256]
    unsigned short* Bzdr2  = Bzcl2 + (size_t)N_CL * HD;      // [4000][256]
    unsigned short* W1senT = Bzdr2 + (size_t)N_DR * HD;      // [3][256][3840]
    unsigned short* W1revT = W1senT + (size_t)RR * HD * KP_CL; // [3][256][1024]
    unsigned short* r1senT = W1revT + (size_t)RR * HD * F_DR;  // [256][1024]
    unsigned short* r1revT = r1senT + (size_t)HD * F_DR;       // [256][3840]
    unsigned short* W2senT = r1revT + (size_t)HD * KP_CL;      // [3][256][256]
    unsigned short* W2revT = W2senT + (size_t)RR * HD * HD;
    unsigned short* r2senT = W2revT + (size_t)RR * HD * HD;    // [256][256]
    unsigned short* r2revT = r2senT + (size_t)HD * HD;
    unsigned short* lin1T  = r2revT + (size_t)HD * HD;         // [256][512]
    int* ip        = (int*)(lin1T + (size_t)HD * 2 * HD);
    int* cnt_sen   = ip;                          // [12000]
    int* fill_sen  = cnt_sen + 12000;             // [12000]
    int* cnt_rev   = fill_sen + 12000;            // [60000]
    int* fill_rev  = cnt_rev + 60000;             // [60000]
    int* base_sen  = fill_rev + 60000;            // [12000]
    int* base_rev  = base_sen + 12000;            // [60000]
    int* ssrc_sen  = base_rev + 60000;            // [500000]
    int* ssrc_rev  = ssrc_sen + 500000;           // [500000]

    dim3 blk(256);

    // ================= CSR build =================
    hipMemsetAsync(cnt_sen, 0, (size_t)(12000 + 12000 + 60000 + 60000) * 4, stream);
    count_seg<<<dim3((NE + 255) / 256), blk, 0, stream>>>(dst_sen, et_sen, NE, cnt_sen);
    count_seg<<<dim3((NE + 255) / 256), blk, 0, stream>>>(dst_rev, et_rev, NE, cnt_rev);
    exscan<<<dim3(1), dim3(1024), 0, stream>>>(cnt_sen, base_sen, N_DR * RR);
    exscan<<<dim3(1), dim3(1024), 0, stream>>>(cnt_rev, base_rev, N_CL * RR);
    scatter_seg<<<dim3((NE + 255) / 256), blk, 0, stream>>>(src_sen, dst_sen, et_sen, NE,
                                                            base_sen, fill_sen, ssrc_sen);
    scatter_seg<<<dim3((NE + 255) / 256), blk, 0, stream>>>(src_rev, dst_rev, et_rev, NE,
                                                            base_rev, fill_rev, ssrc_rev);

    // ================= casts / transposes =================
    {
        long t8;
        t8 = (long)MP_CL * KP_CL / 8;
        cast_pad<<<dim3((unsigned)((t8 + 255) / 256)), blk, 0, stream>>>(x_cl, Axcl, N_CL, F_CL, KP_CL, t8);
        t8 = (long)MP_DR * F_DR / 8;
        cast_pad<<<dim3((unsigned)((t8 + 255) / 256)), blk, 0, stream>>>(x_dr, Axdr, N_DR, F_DR, F_DR, t8);
    }
    cast_t<<<dim3(KP_CL / 32, HD / 32, 3), blk, 0, stream>>>(W1_sen, W1senT, F_CL, HD, KP_CL);
    cast_t<<<dim3(F_DR / 32, HD / 32, 3), blk, 0, stream>>>(W1_rev, W1revT, F_DR, HD, F_DR);
    cast_t<<<dim3(F_DR / 32, HD / 32, 1), blk, 0, stream>>>(r1_sen, r1senT, F_DR, HD, F_DR);
    cast_t<<<dim3(KP_CL / 32, HD / 32, 1), blk, 0, stream>>>(r1_rev, r1revT, F_CL, HD, KP_CL);
    cast_t<<<dim3(HD / 32, HD / 32, 3), blk, 0, stream>>>(W2_sen, W2senT, HD, HD, HD);
    cast_t<<<dim3(HD / 32, HD / 32, 3), blk, 0, stream>>>(W2_rev, W2revT, HD, HD, HD);
    cast_t<<<dim3(HD / 32, HD / 32, 1), blk, 0, stream>>>(r2_sen, r2senT, HD, HD, HD);
    cast_t<<<dim3(HD / 32, HD / 32, 1), blk, 0, stream>>>(r2_rev, r2revT, HD, HD, HD);
    cast_t<<<dim3(512 / 32, HD / 32, 1), blk, 0, stream>>>(lin1_w, lin1T, 2 * HD, HD, 2 * HD);

    // ================= layer 1 (MFMA) =================
    mgemm<<<dim3(2, 157, 3), blk, 0, stream>>>(Axcl, W1senT, h_sen, N_CL, KP_CL, HD);
    mgemm<<<dim3(2, 32, 3), blk, 0, stream>>>(Axdr, W1revT, h_rev, N_DR, F_DR, HD);
    mgemm<<<dim3(2, 32, 1), blk, 0, stream>>>(Axdr, r1senT, root_dr, N_DR, F_DR, HD);
    mgemm<<<dim3(2, 157, 1), blk, 0, stream>>>(Axcl, r1revT, root_cl, N_CL, KP_CL, HD);
    agg_fin<1><<<dim3(N_DR), blk, 0, stream>>>(h_sen, base_sen, cnt_sen, ssrc_sen,
                                               root_dr, b1_sen, Azdr, N_CL);
    agg_fin<1><<<dim3(N_CL), blk, 0, stream>>>(h_rev, base_rev, cnt_rev, ssrc_rev,
                                               root_cl, b1_rev, Azcl, N_DR);

    // ================= layer 2 (MFMA, K=256) =================
    mgemm<<<dim3(2, 157, 3), blk, 0, stream>>>(Azcl, W2senT, h_sen, N_CL, HD, HD);
    mgemm<<<dim3(2, 32, 3), blk, 0, stream>>>(Azdr, W2revT, h_rev, N_DR, HD, HD);
    mgemm<<<dim3(2, 32, 1), blk, 0, stream>>>(Azdr, r2senT, root_dr, N_DR, HD, HD);
    mgemm<<<dim3(2, 157, 1), blk, 0, stream>>>(Azcl, r2revT, root_cl, N_CL, HD, HD);
    agg_fin<0><<<dim3(N_DR), blk, 0, stream>>>(h_sen, base_sen, cnt_sen, ssrc_sen,
                                               root_dr, b2_sen, Bzdr2, N_CL);
    agg_fin<0><<<dim3(N_CL), blk, 0, stream>>>(h_rev, base_rev, cnt_rev, ssrc_rev,
                                               root_cl, b2_rev, Bzcl2, N_DR);

    // ================= decoder (MFMA) =================
    decoder_m<<<dim3(NEL / 64), blk, 0, stream>>>(Bzcl2, Bzdr2, row, col, lin1T,
                                                  lin1_b, lin2_w, lin2_b, out);
}